// Round 8
// baseline (255.023 us; speedup 1.0000x reference)
//
#include <hip/hip_runtime.h>
#include <hip/hip_bf16.h>

typedef __attribute__((ext_vector_type(8))) short bf16x8;
typedef __attribute__((ext_vector_type(4))) short bf16x4;
typedef __attribute__((ext_vector_type(4))) float f32x4;

#define AS1 __attribute__((address_space(1)))
#define AS3 __attribute__((address_space(3)))

// ---------------------------------------------------------------- LayerNorm
__global__ __launch_bounds__(256)
void ln_kernel(const float* __restrict__ x, const float* __restrict__ g,
               const float* __restrict__ b, __hip_bfloat16* __restrict__ out)
{
    const int row = blockIdx.x;
    const float* xr = x + (size_t)row * 768;
    const int t = threadIdx.x;
    float v0 = xr[t], v1 = xr[t + 256], v2 = xr[t + 512];
    float s = v0 + v1 + v2;
    float ss = v0 * v0 + v1 * v1 + v2 * v2;
#pragma unroll
    for (int off = 1; off < 64; off <<= 1) {
        s  += __shfl_xor(s, off, 64);
        ss += __shfl_xor(ss, off, 64);
    }
    __shared__ float red[8];
    const int wv = t >> 6;
    if ((t & 63) == 0) { red[wv] = s; red[wv + 4] = ss; }
    __syncthreads();
    s  = red[0] + red[1] + red[2] + red[3];
    ss = red[4] + red[5] + red[6] + red[7];
    const float mu = s * (1.0f / 768.0f);
    const float rstd = rsqrtf(ss * (1.0f / 768.0f) - mu * mu + 1e-5f);
    __hip_bfloat16* orow = out + (size_t)row * 768;
    orow[t]       = __float2bfloat16((v0 - mu) * rstd * g[t]       + b[t]);
    orow[t + 256] = __float2bfloat16((v1 - mu) * rstd * g[t + 256] + b[t + 256]);
    orow[t + 512] = __float2bfloat16((v2 - mu) * rstd * g[t + 512] + b[t + 512]);
}

// ------------------------------------------------- weight transpose f32->bf16
__global__ __launch_bounds__(256)
void transpose_w(const float* __restrict__ in, __hip_bfloat16* __restrict__ out,
                 int R, int C)
{
    __shared__ float tile[32][33];
    const int c0 = blockIdx.x * 32, r0 = blockIdx.y * 32;
    const int tx = threadIdx.x, ty = threadIdx.y;
#pragma unroll
    for (int i = 0; i < 4; i++)
        tile[ty + i * 8][tx] = in[(size_t)(r0 + ty + i * 8) * C + c0 + tx];
    __syncthreads();
#pragma unroll
    for (int i = 0; i < 4; i++)
        out[(size_t)(c0 + ty + i * 8) * R + r0 + tx] =
            __float2bfloat16(tile[tx][ty + i * 8]);
}

// ---------------------------------------------- QKV weight pack: [H,C,D] f32
__global__ __launch_bounds__(256)
void conv_qkv(const float* __restrict__ wq, const float* __restrict__ wk,
              const float* __restrict__ wv, __hip_bfloat16* __restrict__ out)
{
    const int z = blockIdx.z;
    const int mat = z / 12, h = z % 12;
    const float* w = (mat == 0) ? wq : ((mat == 1) ? wk : wv);
    __shared__ float tile[32][33];
    const int c0 = blockIdx.x * 32;
    const int d0 = blockIdx.y * 32;
    const int tx = threadIdx.x, ty = threadIdx.y;
#pragma unroll
    for (int i = 0; i < 4; i++)
        tile[ty + i * 8][tx] =
            w[(size_t)h * 768 * 64 + (size_t)(c0 + ty + i * 8) * 64 + d0 + tx];
    __syncthreads();
#pragma unroll
    for (int i = 0; i < 4; i++)
        out[(size_t)(mat * 768 + h * 64 + d0 + ty + i * 8) * 768 + c0 + tx] =
            __float2bfloat16(tile[tx][ty + i * 8]);
}

// ------------------------------------------------------------------- GEMM
// C[M,N] = A[M,K] (bf16 row-major) * Bt[N,K]^T. BK=64, XOR-swizzled LDS (T2),
// XCD-chunked work remap (T1). Template BN in {128, 64}:
//   BN=128: 4 waves as 2x2, per-wave 64x64 out (acc[4][4])
//   BN=64 : 4 waves stacked in M, per-wave 32x64 out (acc[2][4]) — used where
//           a 128-wide N grid leaves blocks%256CU slack (proj/FFN2/QKV).
template<int MODE, int BN>
__global__ __launch_bounds__(256)
void gemm_kernel(const __hip_bfloat16* __restrict__ A,
                 const __hip_bfloat16* __restrict__ Bt,
                 const float* __restrict__ bias,
                 const float* __restrict__ res,
                 void* __restrict__ outp,
                 __hip_bfloat16* __restrict__ outK,
                 __hip_bfloat16* __restrict__ outV,
                 int M, int N, int K)
{
    constexpr int MREP = (BN == 128) ? 4 : 2;
    constexpr int BCH  = BN / 32;              // B chunks per thread
    __shared__ alignas(16) char As[128 * 128];
    __shared__ alignas(16) char Bs[BN * 128];
    const int tid = threadIdx.x;
    const int wave = tid >> 6, lane = tid & 63;

    // T1: XCD-chunked remap of linearized workgroup id
    const int nwgx = gridDim.x;
    const int hw = blockIdx.x + nwgx * blockIdx.y;
    const int nwg = nwgx * gridDim.y;
    const int q8 = nwg >> 3;                    // all grids divisible by 8
    const int work = (hw & 7) * q8 + (hw >> 3);
    const int m0 = (work / nwgx) * 128, n0 = (work % nwgx) * BN;

    const int wm = (BN == 128) ? (wave >> 1) * 64 : wave * 32;
    const int wn = (BN == 128) ? (wave & 1) * 64 : 0;
    f32x4 acc[MREP][4] = {};

    int soff[4];
#pragma unroll
    for (int r = 0; r < 4; r++) {
        const int n = tid + 256 * r;
        const int row = n >> 3;
        soff[r] = row * (K * 2) + ((((n & 7) << 4)) ^ ((row & 7) << 4));
    }

    const int fr = lane & 15, fg = lane >> 4;

    for (int k0 = 0; k0 < K; k0 += 64) {
        __syncthreads();
        const char* ga = (const char*)A  + (size_t)m0 * K * 2 + k0 * 2;
        const char* gb = (const char*)Bt + (size_t)n0 * K * 2 + k0 * 2;
#pragma unroll
        for (int r = 0; r < 4; r++)
            __builtin_amdgcn_global_load_lds((const AS1 void*)(ga + soff[r]),
                (AS3 void*)(As + r * 4096 + tid * 16), 16, 0, 0);
#pragma unroll
        for (int r = 0; r < BCH; r++)
            __builtin_amdgcn_global_load_lds((const AS1 void*)(gb + soff[r]),
                (AS3 void*)(Bs + r * 4096 + tid * 16), 16, 0, 0);
        __syncthreads();
        bf16x8 af[MREP][2], bfr[4][2];
#pragma unroll
        for (int i = 0; i < MREP; i++)
#pragma unroll
            for (int ks = 0; ks < 2; ks++)
                af[i][ks] = *(const bf16x8*)(As + (wm + i * 16 + fr) * 128 +
                            ((fg * 16 + ks * 64) ^ ((fr & 7) << 4)));
#pragma unroll
        for (int j = 0; j < 4; j++)
#pragma unroll
            for (int ks = 0; ks < 2; ks++)
                bfr[j][ks] = *(const bf16x8*)(Bs + (wn + j * 16 + fr) * 128 +
                             ((fg * 16 + ks * 64) ^ ((fr & 7) << 4)));
        __builtin_amdgcn_s_setprio(1);
#pragma unroll
        for (int ks = 0; ks < 2; ks++)
#pragma unroll
            for (int i = 0; i < MREP; i++)
#pragma unroll
                for (int j = 0; j < 4; j++)
                    acc[i][j] = __builtin_amdgcn_mfma_f32_16x16x32_bf16(
                        af[i][ks], bfr[j][ks], acc[i][j], 0, 0, 0);
        __builtin_amdgcn_s_setprio(0);
    }

#pragma unroll
    for (int j = 0; j < 4; j++) {
        const int n = n0 + wn + j * 16 + fr;
        if (MODE == 1 && n >= 1536) {
            // V transposed: vbuf[bh][d][t], vector store along t
            const int hh = (n - 1536) >> 6, dd = (n - 1536) & 63;
#pragma unroll
            for (int i = 0; i < MREP; i++) {
                const int m = m0 + wm + i * 16 + fg * 4;
                const int bidx = m >> 11, tt = m & 2047;
                bf16x4 pk;
                __hip_bfloat16* pp = (__hip_bfloat16*)&pk;
#pragma unroll
                for (int r = 0; r < 4; r++)
                    pp[r] = __float2bfloat16(acc[i][j][r]);
                *(bf16x4*)&outV[(((size_t)bidx * 12 + hh) * 64 + dd) * 2048 + tt] = pk;
            }
            continue;
        }
        const float bv = (MODE == 2 || MODE == 3) ? bias[n] : 0.0f;
#pragma unroll
        for (int i = 0; i < MREP; i++) {
#pragma unroll
            for (int r = 0; r < 4; r++) {
                const int m = m0 + wm + i * 16 + fg * 4 + r;
                float v = acc[i][j][r] + bv;
                if (MODE == 3) v = fmaxf(v, 0.0f);
                if (MODE == 2) {
                    ((float*)outp)[(size_t)m * N + n] = res[(size_t)m * N + n] + v;
                } else if (MODE == 1) {
                    __hip_bfloat16* dst; int nc;
                    if (n < 768) { dst = (__hip_bfloat16*)outp; nc = n;
                                   v *= 0.18033688011112042f; /* 0.125*log2e */ }
                    else         { dst = outK; nc = n - 768; }
                    const int hh = nc >> 6, dd = nc & 63;
                    const int bidx = m >> 11, tt = m & 2047;
                    dst[(((size_t)bidx * 12 + hh) * 2048 + tt) * 64 + dd] =
                        __float2bfloat16(v);
                } else {
                    ((__hip_bfloat16*)outp)[(size_t)m * N + n] = __float2bfloat16(v);
                }
            }
        }
    }
}

// ----------------------------------------------------------- causal attention
// Work-balanced paired q-tiles + XCD-local head mapping + MFMA denominator.
// NEW: max-relative scores via MFMA C-operand fold — nm4 = {-mrun} is passed as
// the QK^T accumulator init, so s comes out already (score - mrun): deletes the
// 16 v_sub/iter. Max tree uses v_max3-shaped triples (T17). Cross-lane shuffles
// and the s -= shift fixup run only inside the rare rescale branch.
__global__ __launch_bounds__(256)
void attn_kernel(const __hip_bfloat16* __restrict__ Q,
                 const __hip_bfloat16* __restrict__ Kg,
                 const __hip_bfloat16* __restrict__ Vg,
                 __hip_bfloat16* __restrict__ out)
{
    __shared__ alignas(16) char lds[32768];   // [cur][ K 8KB | V^T 8KB ]
    const int tid = threadIdx.x, wave = tid >> 6, lane = tid & 63;
    const int fr = lane & 15, fg = lane >> 4;

    // XCD-local head mapping: grid is (16, 48), hw = bx' + 16*bh'.
    const int hw = blockIdx.x + 16 * blockIdx.y;
    const int xcd = hw & 7, chunk = hw >> 3;      // 96 chunks per XCD
    const int bh = xcd * 6 + (chunk >> 4);        // 6 heads per XCD
    const int bx = chunk & 15;                    // 16 q-blocks per head

    const int b = bh / 12, h = bh % 12;
    const __hip_bfloat16* qb = Q  + (size_t)bh * 2048 * 64;
    const __hip_bfloat16* kb = Kg + (size_t)bh * 2048 * 64;
    const __hip_bfloat16* vb = Vg + (size_t)bh * 2048 * 64;   // [64 d][2048 t]

    int ksoff[2], vsoff[2];
#pragma unroll
    for (int r = 0; r < 2; r++) {
        const int n = wave * 64 + lane + 256 * r;
        const int row = n >> 3;
        const int swz = (((n & 7) << 4)) ^ ((row & 7) << 4);
        ksoff[r] = row * 128  + swz;
        vsoff[r] = row * 4096 + swz;
    }

    auto STAGE = [&](int cur, int kv0) {
        const char* kx = (const char*)kb + (size_t)kv0 * 128;
        const char* vx = (const char*)vb + (size_t)kv0 * 2;
#pragma unroll
        for (int r = 0; r < 2; r++) {
            __builtin_amdgcn_global_load_lds((const AS1 void*)(kx + ksoff[r]),
                (AS3 void*)(lds + cur * 16384 + r * 4096 + wave * 1024), 16, 0, 0);
            __builtin_amdgcn_global_load_lds((const AS1 void*)(vx + vsoff[r]),
                (AS3 void*)(lds + cur * 16384 + 8192 + r * 4096 + wave * 1024), 16, 0, 0);
        }
    };

    const bf16x4 ones = {(short)0x3F80, (short)0x3F80,
                         (short)0x3F80, (short)0x3F80};   // bf16 1.0 x4

#pragma unroll
    for (int pass = 0; pass < 2; ++pass) {
        const int g = pass ? (31 - bx) : bx;
        const int q0w = g * 64 + wave * 16;
        const int qv = q0w + fr;

        bf16x8 qf0 = *(const bf16x8*)(qb + (size_t)qv * 64 + fg * 8);
        bf16x8 qf1 = *(const bf16x8*)(qb + (size_t)qv * 64 + 32 + fg * 8);

        f32x4 o[4] = {};
        f32x4 o_l = {};                 // running denominator (all rows equal)
        f32x4 nm4 = {1e4f, 1e4f, 1e4f, 1e4f};   // = -mrun (mrun starts -1e4)
        const int NT = g + 1;

        STAGE(0, 0);
        __syncthreads();
        int cur = 0;

        for (int t = 0; t < NT; ++t) {
            if (t + 1 < NT) STAGE(cur ^ 1, (t + 1) << 6);
            const int kv0 = t << 6;
            const char* Kb = lds + cur * 16384;
            const char* Vb = Kb + 8192;
            bf16x8 kf[4][2];
#pragma unroll
            for (int c = 0; c < 4; c++)
#pragma unroll
                for (int hh = 0; hh < 2; hh++)
                    kf[c][hh] = *(const bf16x8*)(Kb + (16 * c + fr) * 128 +
                                ((hh * 64 + fg * 16) ^ ((fr & 7) << 4)));
            f32x4 s[4];
            __builtin_amdgcn_s_setprio(1);
#pragma unroll
            for (int c = 0; c < 4; c++) {
                // C-operand = nm4 (read-only): s comes out max-relative
                s[c] = __builtin_amdgcn_mfma_f32_16x16x32_bf16(
                    kf[c][0], qf0, nm4, 0, 0, 0);
                s[c] = __builtin_amdgcn_mfma_f32_16x16x32_bf16(
                    kf[c][1], qf1, s[c], 0, 0, 0);
            }
            __builtin_amdgcn_s_setprio(0);
            if (t == NT - 1) {
#pragma unroll
                for (int c = 0; c < 4; c++)
#pragma unroll
                    for (int r = 0; r < 4; r++)
                        if (kv0 + 16 * c + 4 * fg + r > qv) s[c][r] = -1e30f;
            }
            // max via v_max3-shaped triples (T17)
            const float a0 = fmaxf(fmaxf(s[0][0], s[0][1]), s[0][2]);
            const float a1 = fmaxf(fmaxf(s[0][3], s[1][0]), s[1][1]);
            const float a2 = fmaxf(fmaxf(s[1][2], s[1][3]), s[2][0]);
            const float a3 = fmaxf(fmaxf(s[2][1], s[2][2]), s[2][3]);
            const float a4 = fmaxf(fmaxf(s[3][0], s[3][1]), s[3][2]);
            const float b0 = fmaxf(fmaxf(a0, a1), a2);
            const float b1 = fmaxf(fmaxf(a3, a4), s[3][3]);
            const float tm = fmaxf(b0, b1);
            if (!__all(tm <= 8.f)) {             // defer-max (T13), relative
                float tf = fmaxf(tm, __shfl_xor(tm, 16, 64));
                tf = fmaxf(tf, __shfl_xor(tf, 32, 64));   // tf > 8 > 0
                const float al = exp2f(-tf);
#pragma unroll
                for (int c = 0; c < 4; c++)
#pragma unroll
                    for (int r = 0; r < 4; r++) s[c][r] -= tf;
#pragma unroll
                for (int i = 0; i < 4; i++)
#pragma unroll
                    for (int e = 0; e < 4; e++) o[i][e] *= al;
#pragma unroll
                for (int e = 0; e < 4; e++) { o_l[e] *= al; nm4[e] -= tf; }
            }
            bf16x4 pf[4];
#pragma unroll
            for (int c = 0; c < 4; c++) {
                const float p0 = exp2f(s[c][0]), p1 = exp2f(s[c][1]);
                const float p2 = exp2f(s[c][2]), p3 = exp2f(s[c][3]);
                __hip_bfloat16* pp = (__hip_bfloat16*)&pf[c];
                pp[0] = __float2bfloat16(p0); pp[1] = __float2bfloat16(p1);
                pp[2] = __float2bfloat16(p2); pp[3] = __float2bfloat16(p3);
            }
            bf16x4 vf[4][4];
#pragma unroll
            for (int i = 0; i < 4; i++)
#pragma unroll
                for (int c = 0; c < 4; c++)
                    vf[i][c] = *(const bf16x4*)(Vb + (16 * i + fr) * 128 +
                                ((32 * c + 8 * fg) ^ ((fr & 7) << 4)));
            __builtin_amdgcn_s_setprio(1);
#pragma unroll
            for (int c = 0; c < 4; c++)          // denominator: P column-sums
                o_l = __builtin_amdgcn_mfma_f32_16x16x16bf16_1k(
                    ones, pf[c], o_l, 0, 0, 0);
#pragma unroll
            for (int i = 0; i < 4; i++)
#pragma unroll
                for (int c = 0; c < 4; c++)
                    o[i] = __builtin_amdgcn_mfma_f32_16x16x16bf16_1k(
                        vf[i][c], pf[c], o[i], 0, 0, 0);
            __builtin_amdgcn_s_setprio(0);
            __syncthreads();
            cur ^= 1;
        }

        const float inv = 1.0f / o_l[0];
        __hip_bfloat16* ob = out + ((size_t)(b * 2048 + qv)) * 768 + h * 64;
#pragma unroll
        for (int i = 0; i < 4; i++) {
            bf16x4 pk;
            __hip_bfloat16* pp = (__hip_bfloat16*)&pk;
#pragma unroll
            for (int r = 0; r < 4; r++)
                pp[r] = __float2bfloat16(o[i][r] * inv);
            *(bf16x4*)(ob + 16 * i + 4 * fg) = pk;
        }
    }
}

// ---------------------------------------------------------------------------
extern "C" void kernel_launch(void* const* d_in, const int* in_sizes, int n_in,
                              void* d_out, int out_size, void* d_ws, size_t ws_size,
                              hipStream_t stream)
{
    const float* x      = (const float*)d_in[0];
    const float* wq     = (const float*)d_in[1];
    const float* wk     = (const float*)d_in[2];
    const float* wv     = (const float*)d_in[3];
    const float* w_proj = (const float*)d_in[4];
    const float* b_proj = (const float*)d_in[5];
    const float* w1     = (const float*)d_in[6];
    const float* b1     = (const float*)d_in[7];
    const float* w2     = (const float*)d_in[8];
    const float* b2     = (const float*)d_in[9];
    const float* ln1_g  = (const float*)d_in[10];
    const float* ln1_b  = (const float*)d_in[11];
    const float* ln2_g  = (const float*)d_in[12];
    const float* ln2_b  = (const float*)d_in[13];
    float* out = (float*)d_out;

    char* w = (char*)d_ws;
    size_t off = 0;
    auto alloc = [&](size_t bytes) {
        void* p = w + off;
        off += (bytes + 255) & ~(size_t)255;
        return p;
    };
    __hip_bfloat16* h_ln    = (__hip_bfloat16*)alloc(8192ull * 768 * 2);
    __hip_bfloat16* wt_qkv  = (__hip_bfloat16*)alloc(2304ull * 768 * 2);
    __hip_bfloat16* wt_proj = (__hip_bfloat16*)alloc(768ull * 768 * 2);
    __hip_bfloat16* wt1     = (__hip_bfloat16*)alloc(3072ull * 768 * 2);
    __hip_bfloat16* wt2     = (__hip_bfloat16*)alloc(768ull * 3072 * 2);
    __hip_bfloat16* qbuf    = (__hip_bfloat16*)alloc(8192ull * 768 * 2);
    __hip_bfloat16* kbuf    = (__hip_bfloat16*)alloc(8192ull * 768 * 2);
    __hip_bfloat16* vbuf    = (__hip_bfloat16*)alloc(8192ull * 768 * 2);
    __hip_bfloat16* attn_o  = (__hip_bfloat16*)alloc(8192ull * 768 * 2);
    float*          x1      = (float*)alloc(8192ull * 768 * 4);
    __hip_bfloat16* h2      = (__hip_bfloat16*)alloc(8192ull * 768 * 2);
    __hip_bfloat16* a1      = qbuf;  // alias: q/k/v/attn_o dead by FFN1

    conv_qkv<<<dim3(24, 2, 36), dim3(32, 8), 0, stream>>>(wq, wk, wv, wt_qkv);
    transpose_w<<<dim3(24, 24), dim3(32, 8), 0, stream>>>(w_proj, wt_proj, 768, 768);
    transpose_w<<<dim3(96, 24), dim3(32, 8), 0, stream>>>(w1, wt1, 768, 3072);
    transpose_w<<<dim3(24, 96), dim3(32, 8), 0, stream>>>(w2, wt2, 3072, 768);

    ln_kernel<<<8192, 256, 0, stream>>>(x, ln1_g, ln1_b, h_ln);
    gemm_kernel<1, 64><<<dim3(36, 64), 256, 0, stream>>>(
        h_ln, wt_qkv, nullptr, nullptr, qbuf, kbuf, vbuf, 8192, 2304, 768);
    attn_kernel<<<dim3(16, 48), 256, 0, stream>>>(qbuf, kbuf, vbuf, attn_o);
    gemm_kernel<2, 64><<<dim3(12, 64), 256, 0, stream>>>(
        attn_o, wt_proj, b_proj, x, x1, nullptr, nullptr, 8192, 768, 768);

    ln_kernel<<<8192, 256, 0, stream>>>(x1, ln2_g, ln2_b, h2);
    gemm_kernel<3, 128><<<dim3(24, 64), 256, 0, stream>>>(
        h2, wt1, b1, nullptr, a1, nullptr, nullptr, 8192, 3072, 768);
    gemm_kernel<2, 64><<<dim3(12, 64), 256, 0, stream>>>(
        a1, wt2, b2, x1, out, nullptr, nullptr, 8192, 768, 3072);
}